// Round 1
// baseline (942.684 us; speedup 1.0000x reference)
//
#include <hip/hip_runtime.h>
#include <math.h>

#define D_MODEL 2048
#define D_STATE 16
#define D_EVENT 32
#define BATCH   2048

typedef __attribute__((ext_vector_type(4))) float f32x4;
typedef __attribute__((ext_vector_type(8))) short short8;
typedef __attribute__((ext_vector_type(8))) __bf16 bf16x8;
typedef __attribute__((ext_vector_type(4))) unsigned short us4;

// fp32 -> bf16 round-to-nearest-even (inputs are well-behaved, no NaN/Inf handling)
__device__ inline unsigned short f2bf(float f) {
  unsigned int u = __builtin_bit_cast(unsigned int, f);
  u += 0x7fffu + ((u >> 16) & 1u);
  return (unsigned short)(u >> 16);
}

// ---------------------------------------------------------------------------
// Kernel 1: bf16 conversions (x, Wd, event, We, A_We) + A_base = -exp(clip(A_log,-3,1))
// ---------------------------------------------------------------------------
__global__ __launch_bounds__(256) void prep_kernel(
    const float* __restrict__ x, const float* __restrict__ wd,
    const float* __restrict__ ev, const float* __restrict__ we,
    const float* __restrict__ awe, const float* __restrict__ alog,
    unsigned short* __restrict__ xb, unsigned short* __restrict__ wdb,
    unsigned short* __restrict__ evb, unsigned short* __restrict__ web,
    unsigned short* __restrict__ aweb, float* __restrict__ abase)
{
  const int t = blockIdx.x * 256 + threadIdx.x;
  if (t < (BATCH * D_MODEL) / 4) {
    f32x4 v = *(const f32x4*)(x + (size_t)t * 4);
    f32x4 w = *(const f32x4*)(wd + (size_t)t * 4);
    us4 ov, ow;
#pragma unroll
    for (int r = 0; r < 4; ++r) { ov[r] = f2bf(v[r]); ow[r] = f2bf(w[r]); }
    *(us4*)(xb + (size_t)t * 4) = ov;
    *(us4*)(wdb + (size_t)t * 4) = ow;
  }
  if (t < (BATCH * D_EVENT) / 4) {   // == (D_MODEL*D_EVENT)/4
    f32x4 e = *(const f32x4*)(ev + (size_t)t * 4);
    f32x4 s = *(const f32x4*)(we + (size_t)t * 4);
    f32x4 a = *(const f32x4*)(awe + (size_t)t * 4);
    us4 oe, os, oa;
#pragma unroll
    for (int r = 0; r < 4; ++r) { oe[r] = f2bf(e[r]); os[r] = f2bf(s[r]); oa[r] = f2bf(a[r]); }
    *(us4*)(evb + (size_t)t * 4) = oe;
    *(us4*)(web + (size_t)t * 4) = os;
    *(us4*)(aweb + (size_t)t * 4) = oa;
  }
  if (t < (D_MODEL * D_STATE) / 4) {
    f32x4 a = *(const f32x4*)(alog + (size_t)t * 4);
    f32x4 o;
#pragma unroll
    for (int r = 0; r < 4; ++r) {
      float c = fminf(fmaxf(a[r], -3.0f), 1.0f);
      o[r] = -expf(c);
    }
    *(f32x4*)(abase + (size_t)t * 4) = o;
  }
}

// ---------------------------------------------------------------------------
// Kernel 2: per-row B_t = silu(x@B_W1.T + b1)@B_W2.T + b2 + ev@B_We.T ; C_t = x@C_W.T
// one block (4 waves) per batch row; 48 K=2048 dots -> 12 per wave
// ---------------------------------------------------------------------------
__global__ __launch_bounds__(256) void bc_kernel(
    const float* __restrict__ x, const float* __restrict__ ev,
    const float* __restrict__ BW1, const float* __restrict__ Bb1,
    const float* __restrict__ BW2, const float* __restrict__ Bb2,
    const float* __restrict__ BWe, const float* __restrict__ CW,
    float* __restrict__ Bt, float* __restrict__ Ct)
{
  __shared__ float xs[D_MODEL];
  __shared__ float t1s[2 * D_STATE];
  const int b = blockIdx.x, tid = threadIdx.x;
  f32x4* xs4 = (f32x4*)xs;
  const f32x4* xg = (const f32x4*)(x + (size_t)b * D_MODEL);
  xs4[tid] = xg[tid];
  xs4[tid + 256] = xg[tid + 256];
  __syncthreads();
  const int wave = tid >> 6, lane = tid & 63;
#pragma unroll 1
  for (int jj = 0; jj < 12; ++jj) {
    const int j = wave * 12 + jj;
    const float* wr = (j < 32) ? (BW1 + (size_t)j * D_MODEL)
                               : (CW + (size_t)(j - 32) * D_MODEL);
    float s = 0.f;
    for (int k = lane; k < D_MODEL; k += 64) s += xs[k] * wr[k];
#pragma unroll
    for (int o = 32; o > 0; o >>= 1) s += __shfl_xor(s, o);
    if (lane == 0) {
      if (j < 32) {
        float z = s + Bb1[j];
        t1s[j] = z / (1.f + expf(-z));   // silu
      } else {
        Ct[b * D_STATE + (j - 32)] = s;
      }
    }
  }
  __syncthreads();
  if (tid < D_STATE) {
    const int n = tid;
    float s = Bb2[n];
    const float* w2 = BW2 + n * (2 * D_STATE);
    const float* we = BWe + n * D_EVENT;
    const float* eb = ev + (size_t)b * D_EVENT;
#pragma unroll
    for (int k = 0; k < 2 * D_STATE; ++k) s += t1s[k] * w2[k];
#pragma unroll
    for (int k = 0; k < D_EVENT; ++k) s += eb[k] * we[k];
    Bt[b * D_STATE + n] = s;
  }
}

// ---------------------------------------------------------------------------
// Kernel 3 (FUSED): delta GEMM + pole GEMM + state update + y, one kernel.
//   64(batch) x 128(d_model) tile, BK=32, global_load_lds width 16.
//   512 blocks -> 2 blocks/CU (__launch_bounds__(256,2)): one block's
//   BW-bound epilogue overlaps the other's MFMA K-loop.
//   acc  = x @ Wd.T  (+ ev @ We.T augmented K-step)   -> delta after softplus
//   acc2 = ev @ A_We.T                                 -> event pole, same (b,d) layout
//   epilogue: delta=min(softplus(acc+bd),2); A_bar=exp2(delta*log2e*(abase+pole));
//             h = A_bar*h_prev + delta*Bt*x ; y = sum_n h*Ct + D*x
// ---------------------------------------------------------------------------
__device__ inline void gld_lds16(const unsigned short* g, unsigned short* l) {
  __builtin_amdgcn_global_load_lds(
      (const __attribute__((address_space(1))) unsigned int*)g,
      (__attribute__((address_space(3))) unsigned int*)l, 16, 0, 0);
}

__global__ __launch_bounds__(256, 2) void gemm_update(
    const unsigned short* __restrict__ xb, const unsigned short* __restrict__ wdb,
    const unsigned short* __restrict__ evb, const unsigned short* __restrict__ web,
    const unsigned short* __restrict__ aweb,
    const float* __restrict__ bd, const float* __restrict__ x,
    const float* __restrict__ hprev, const float* __restrict__ abase,
    const float* __restrict__ Bt, const float* __restrict__ Ct,
    const float* __restrict__ Dv,
    float* __restrict__ y, float* __restrict__ h)
{
  // As: [64x32] x-tile (4KB) ; augmented step also uses As+2048 for aweb [128x32]
  __shared__ unsigned short As[6144];
  __shared__ unsigned short Bs[128 * 32];
  const int tid = threadIdx.x;
  const int wave = tid >> 6, lane = tid & 63;
  const int r16 = lane & 15, q = lane >> 4;
  const int d0 = blockIdx.x * 128, b0 = blockIdx.y * 64;
  const int wm = (wave >> 1) * 32, wn = (wave & 1) * 64;   // wave sub-tile: 32(b) x 64(d)
  const int srow = tid >> 2, skp = tid & 3;  // staging: row=tid>>2, kpart=tid&3 (16B each)
  f32x4 acc[2][4] = {};
  f32x4 acc2[2][4] = {};

  for (int kt = 0; kt < D_MODEL / 32; ++kt) {
    const int k0 = kt * 32;
    // A-tile: 64x32 bf16 = 1 chunk; B-tile: 128x32 = 2 chunks
    gld_lds16(xb + (size_t)(b0 + srow) * D_MODEL + k0 + skp * 8, As + wave * 512);
    gld_lds16(wdb + (size_t)(d0 + srow) * D_MODEL + k0 + skp * 8, Bs + wave * 512);
    gld_lds16(wdb + (size_t)(d0 + 64 + srow) * D_MODEL + k0 + skp * 8, Bs + 2048 + wave * 512);
    __syncthreads();
    bf16x8 af[2], bf[4];
#pragma unroll
    for (int i = 0; i < 2; ++i)
      af[i] = __builtin_bit_cast(bf16x8, *(const short8*)(As + (wm + i * 16 + r16) * 32 + q * 8));
#pragma unroll
    for (int j = 0; j < 4; ++j)
      bf[j] = __builtin_bit_cast(bf16x8, *(const short8*)(Bs + (wn + j * 16 + r16) * 32 + q * 8));
#pragma unroll
    for (int i = 0; i < 2; ++i)
#pragma unroll
      for (int j = 0; j < 4; ++j)
        acc[i][j] = __builtin_amdgcn_mfma_f32_16x16x32_bf16(af[i], bf[j], acc[i][j], 0, 0, 0);
    __syncthreads();
  }
  {  // augmented K-step (K=32): acc += ev@We.T ; acc2 = ev@A_We.T (same ev A-frag)
    gld_lds16(evb + (size_t)(b0 + srow) * D_EVENT + skp * 8, As + wave * 512);
    gld_lds16(web + (size_t)(d0 + srow) * D_EVENT + skp * 8, Bs + wave * 512);
    gld_lds16(web + (size_t)(d0 + 64 + srow) * D_EVENT + skp * 8, Bs + 2048 + wave * 512);
    gld_lds16(aweb + (size_t)(d0 + srow) * D_EVENT + skp * 8, As + 2048 + wave * 512);
    gld_lds16(aweb + (size_t)(d0 + 64 + srow) * D_EVENT + skp * 8, As + 4096 + wave * 512);
    __syncthreads();
    bf16x8 af[2], bf[4], bfa[4];
#pragma unroll
    for (int i = 0; i < 2; ++i)
      af[i] = __builtin_bit_cast(bf16x8, *(const short8*)(As + (wm + i * 16 + r16) * 32 + q * 8));
#pragma unroll
    for (int j = 0; j < 4; ++j) {
      bf[j]  = __builtin_bit_cast(bf16x8, *(const short8*)(Bs + (wn + j * 16 + r16) * 32 + q * 8));
      bfa[j] = __builtin_bit_cast(bf16x8, *(const short8*)(As + 2048 + (wn + j * 16 + r16) * 32 + q * 8));
    }
#pragma unroll
    for (int i = 0; i < 2; ++i)
#pragma unroll
      for (int j = 0; j < 4; ++j) {
        acc[i][j]  = __builtin_amdgcn_mfma_f32_16x16x32_bf16(af[i], bf[j],  acc[i][j],  0, 0, 0);
        acc2[i][j] = __builtin_amdgcn_mfma_f32_16x16x32_bf16(af[i], bfa[j], acc2[i][j], 0, 0, 0);
      }
  }
  // epilogue. C/D layout: col=lane&15 -> d ; row=(lane>>4)*4+reg -> b
#pragma unroll
  for (int j = 0; j < 4; ++j) {
    const int d = d0 + wn + j * 16 + r16;
    const float bdv = bd[d];
    const float Dd = Dv[d];
    const f32x4* ab4 = (const f32x4*)(abase + (size_t)d * D_STATE);
    f32x4 ab0 = ab4[0], ab1 = ab4[1], ab2 = ab4[2], ab3 = ab4[3];
#pragma unroll
    for (int i = 0; i < 2; ++i) {
#pragma unroll
      for (int r = 0; r < 4; ++r) {
        const int b = b0 + wm + i * 16 + q * 4 + r;
        const size_t pid = (size_t)b * D_MODEL + d;
        float pre = acc[i][j][r] + bdv;
        float sp = fmaxf(pre, 0.f) + log1pf(__expf(-fabsf(pre)));
        float dlt = fminf(sp, 2.0f);
        const float pole = acc2[i][j][r];
        const float xv = x[pid];
        const float dl2 = dlt * 1.4426950408889634f;  // delta * log2(e)
        const float bx = dlt * xv;
        const f32x4* hp4 = (const f32x4*)(hprev + pid * D_STATE);
        const f32x4* bt4 = (const f32x4*)(Bt + (size_t)b * D_STATE);
        const f32x4* ct4 = (const f32x4*)(Ct + (size_t)b * D_STATE);
        f32x4* hn4 = (f32x4*)(h + pid * D_STATE);
        const f32x4 abv[4] = {ab0, ab1, ab2, ab3};
        float yp = 0.f;
#pragma unroll
        for (int s = 0; s < 4; ++s) {
          f32x4 hp = hp4[s], bt = bt4[s], ct = ct4[s], ab = abv[s], hn;
#pragma unroll
          for (int u = 0; u < 4; ++u) {
            float abar = exp2f(dl2 * (ab[u] + pole));
            float hv = abar * hp[u] + bx * bt[u];
            hn[u] = hv;
            yp += hv * ct[u];
          }
          hn4[s] = hn;
        }
        y[pid] = yp + Dd * xv;
      }
    }
  }
}

// ---------------------------------------------------------------------------
extern "C" void kernel_launch(void* const* d_in, const int* in_sizes, int n_in,
                              void* d_out, int out_size, void* d_ws, size_t ws_size,
                              hipStream_t stream) {
  const float* x     = (const float*)d_in[0];
  const float* hprev = (const float*)d_in[1];
  const float* ev    = (const float*)d_in[2];
  const float* alog  = (const float*)d_in[3];
  const float* Dv    = (const float*)d_in[4];
  const float* Wd    = (const float*)d_in[5];
  const float* bd    = (const float*)d_in[6];
  const float* We    = (const float*)d_in[7];
  const float* BW1   = (const float*)d_in[8];
  const float* Bb1   = (const float*)d_in[9];
  const float* BW2   = (const float*)d_in[10];
  const float* Bb2   = (const float*)d_in[11];
  const float* BWe   = (const float*)d_in[12];
  const float* AWe   = (const float*)d_in[13];
  const float* CW    = (const float*)d_in[14];

  float* y = (float*)d_out;                           // (B, D_MODEL)
  float* h = (float*)d_out + (size_t)BATCH * D_MODEL; // (B, D_MODEL, D_STATE)

  // workspace layout (bytes): ~16.75 MiB total
  char* ws = (char*)d_ws;
  unsigned short* xb   = (unsigned short*)(ws);                      // 8 MiB
  unsigned short* wdb  = (unsigned short*)(ws + (8u << 20));         // 8 MiB
  float* Bt            = (float*)(ws + (16u << 20));                 // 128 KiB
  float* Ct            = (float*)(ws + (16u << 20) + (128u << 10));  // 128 KiB
  float* abase         = (float*)(ws + (16u << 20) + (256u << 10));  // 128 KiB
  unsigned short* evb  = (unsigned short*)(ws + (16u << 20) + (384u << 10)); // 128 KiB
  unsigned short* web  = (unsigned short*)(ws + (16u << 20) + (512u << 10)); // 128 KiB
  unsigned short* aweb = (unsigned short*)(ws + (16u << 20) + (640u << 10)); // 128 KiB

  hipLaunchKernelGGL(prep_kernel, dim3((BATCH * D_MODEL) / 4 / 256), dim3(256), 0, stream,
                     x, Wd, ev, We, AWe, alog, xb, wdb, evb, web, aweb, abase);
  hipLaunchKernelGGL(bc_kernel, dim3(BATCH), dim3(256), 0, stream,
                     x, ev, BW1, Bb1, BW2, Bb2, BWe, CW, Bt, Ct);
  hipLaunchKernelGGL(gemm_update, dim3(D_MODEL / 128, BATCH / 64), dim3(256), 0, stream,
                     xb, wdb, evb, web, aweb, bd, x, hprev, abase, Bt, Ct, Dv, y, h);
}

// Round 2
// 707.479 us; speedup vs baseline: 1.3325x; 1.3325x over previous
//
#include <hip/hip_runtime.h>
#include <math.h>

#define D_MODEL 2048
#define D_STATE 16
#define D_EVENT 32
#define BATCH   2048

typedef __attribute__((ext_vector_type(4))) float f32x4;
typedef __attribute__((ext_vector_type(8))) short short8;
typedef __attribute__((ext_vector_type(8))) __bf16 bf16x8;
typedef __attribute__((ext_vector_type(4))) unsigned short us4;

// fp32 -> bf16 round-to-nearest-even (inputs are well-behaved, no NaN/Inf handling)
__device__ inline unsigned short f2bf(float f) {
  unsigned int u = __builtin_bit_cast(unsigned int, f);
  u += 0x7fffu + ((u >> 16) & 1u);
  return (unsigned short)(u >> 16);
}

// ---------------------------------------------------------------------------
// Kernel 1: bf16 conversions (x, Wd, event, We) + A_base = -exp(clip(A_log,-3,1))
// ---------------------------------------------------------------------------
__global__ __launch_bounds__(256) void prep_kernel(
    const float* __restrict__ x, const float* __restrict__ wd,
    const float* __restrict__ ev, const float* __restrict__ we,
    const float* __restrict__ alog,
    unsigned short* __restrict__ xb, unsigned short* __restrict__ wdb,
    unsigned short* __restrict__ evb, unsigned short* __restrict__ web,
    float* __restrict__ abase)
{
  const int t = blockIdx.x * 256 + threadIdx.x;
  if (t < (BATCH * D_MODEL) / 4) {
    f32x4 v = *(const f32x4*)(x + (size_t)t * 4);
    f32x4 w = *(const f32x4*)(wd + (size_t)t * 4);
    us4 ov, ow;
#pragma unroll
    for (int r = 0; r < 4; ++r) { ov[r] = f2bf(v[r]); ow[r] = f2bf(w[r]); }
    *(us4*)(xb + (size_t)t * 4) = ov;
    *(us4*)(wdb + (size_t)t * 4) = ow;
  }
  if (t < (BATCH * D_EVENT) / 4) {   // == (D_MODEL*D_EVENT)/4
    f32x4 e = *(const f32x4*)(ev + (size_t)t * 4);
    f32x4 s = *(const f32x4*)(we + (size_t)t * 4);
    us4 oe, os;
#pragma unroll
    for (int r = 0; r < 4; ++r) { oe[r] = f2bf(e[r]); os[r] = f2bf(s[r]); }
    *(us4*)(evb + (size_t)t * 4) = oe;
    *(us4*)(web + (size_t)t * 4) = os;
  }
  if (t < (D_MODEL * D_STATE) / 4) {
    f32x4 a = *(const f32x4*)(alog + (size_t)t * 4);
    f32x4 o;
#pragma unroll
    for (int r = 0; r < 4; ++r) {
      float c = fminf(fmaxf(a[r], -3.0f), 1.0f);
      o[r] = -expf(c);
    }
    *(f32x4*)(abase + (size_t)t * 4) = o;
  }
}

// ---------------------------------------------------------------------------
// Kernel 2 (v2): B_t / C_t with 4 batch rows per block.
//   Round-0 version read all 48 weight rows (392 KB) once PER batch row ->
//   ~800 MB of L2 traffic (~23 us). Batching 4 rows cuts that 4x.
//   x rows staged in LDS (32 KB); weights stream through registers;
//   each wave owns 12 of the 48 output columns for all 4 rows.
// ---------------------------------------------------------------------------
__global__ __launch_bounds__(256) void bc_kernel(
    const float* __restrict__ x, const float* __restrict__ ev,
    const float* __restrict__ BW1, const float* __restrict__ Bb1,
    const float* __restrict__ BW2, const float* __restrict__ Bb2,
    const float* __restrict__ BWe, const float* __restrict__ CW,
    float* __restrict__ Bt, float* __restrict__ Ct)
{
  __shared__ float xs[4][D_MODEL];      // 32 KB
  __shared__ float t1s[4][2 * D_STATE]; // silu(x@BW1.T+b1) per row
  const int tid = threadIdx.x;
  const int b0 = blockIdx.x * 4;
  {
    const f32x4* xg = (const f32x4*)(x + (size_t)b0 * D_MODEL);
    f32x4* xs4 = (f32x4*)xs;
#pragma unroll
    for (int i = 0; i < 8; ++i) xs4[tid + 256 * i] = xg[tid + 256 * i];
  }
  __syncthreads();
  const int wave = tid >> 6, lane = tid & 63;

  float acc[12][4] = {};
#pragma unroll 1
  for (int it = 0; it < 8; ++it) {
    const int k = (it * 64 + lane) * 4;
    f32x4 xr0 = *(const f32x4*)&xs[0][k];
    f32x4 xr1 = *(const f32x4*)&xs[1][k];
    f32x4 xr2 = *(const f32x4*)&xs[2][k];
    f32x4 xr3 = *(const f32x4*)&xs[3][k];
#pragma unroll
    for (int jj = 0; jj < 12; ++jj) {
      const int j = wave * 12 + jj;
      const float* wr = (j < 32) ? (BW1 + (size_t)j * D_MODEL)
                                 : (CW + (size_t)(j - 32) * D_MODEL);
      f32x4 wv = *(const f32x4*)(wr + k);
      acc[jj][0] += xr0[0]*wv[0] + xr0[1]*wv[1] + xr0[2]*wv[2] + xr0[3]*wv[3];
      acc[jj][1] += xr1[0]*wv[0] + xr1[1]*wv[1] + xr1[2]*wv[2] + xr1[3]*wv[3];
      acc[jj][2] += xr2[0]*wv[0] + xr2[1]*wv[1] + xr2[2]*wv[2] + xr2[3]*wv[3];
      acc[jj][3] += xr3[0]*wv[0] + xr3[1]*wv[1] + xr3[2]*wv[2] + xr3[3]*wv[3];
    }
  }
  // reduce each of the 48 partials across the wave
#pragma unroll
  for (int jj = 0; jj < 12; ++jj)
#pragma unroll
    for (int r = 0; r < 4; ++r) {
      float s = acc[jj][r];
#pragma unroll
      for (int o = 32; o > 0; o >>= 1) s += __shfl_xor(s, o);
      acc[jj][r] = s;
    }
  if (lane == 0) {
#pragma unroll
    for (int jj = 0; jj < 12; ++jj) {
      const int j = wave * 12 + jj;
#pragma unroll
      for (int r = 0; r < 4; ++r) {
        const float s = acc[jj][r];
        if (j < 32) {
          float z = s + Bb1[j];
          t1s[r][j] = z / (1.f + expf(-z));   // silu
        } else {
          Ct[(b0 + r) * D_STATE + (j - 32)] = s;
        }
      }
    }
  }
  __syncthreads();
  if (tid < 64) {
    const int row = tid >> 4, n = tid & 15;
    float s = Bb2[n];
    const float* w2 = BW2 + n * (2 * D_STATE);
    const float* we = BWe + n * D_EVENT;
    const float* eb = ev + (size_t)(b0 + row) * D_EVENT;
#pragma unroll
    for (int k = 0; k < 2 * D_STATE; ++k) s += t1s[row][k] * w2[k];
#pragma unroll
    for (int k = 0; k < D_EVENT; ++k) s += eb[k] * we[k];
    Bt[(b0 + row) * D_STATE + n] = s;
  }
}

// ---------------------------------------------------------------------------
// Kernel 3 (v2): delta = min(softplus(x@Wd.T + bd + ev@We.T), 2) via bf16 MFMA.
//   64(batch) x 128(d_model) tile, BK=32 -> 512 blocks = 2 blocks/CU
//   (__launch_bounds__(256,2), 12 KB LDS) so a co-resident block hides the
//   per-K-step barrier drain that capped the 128x128/256-block version.
//   K-loop structure is the round-1-verified one (minus the fused epilogue).
// ---------------------------------------------------------------------------
__device__ inline void gld_lds16(const unsigned short* g, unsigned short* l) {
  __builtin_amdgcn_global_load_lds(
      (const __attribute__((address_space(1))) unsigned int*)g,
      (__attribute__((address_space(3))) unsigned int*)l, 16, 0, 0);
}

__global__ __launch_bounds__(256, 2) void gemm_delta(
    const unsigned short* __restrict__ xb, const unsigned short* __restrict__ wdb,
    const unsigned short* __restrict__ evb, const unsigned short* __restrict__ web,
    const float* __restrict__ bd, float* __restrict__ delta)
{
  __shared__ unsigned short As[64 * 32];    // 4 KB
  __shared__ unsigned short Bs[128 * 32];   // 8 KB
  const int tid = threadIdx.x;
  const int wave = tid >> 6, lane = tid & 63;
  const int r16 = lane & 15, q = lane >> 4;
  const int d0 = blockIdx.x * 128, b0 = blockIdx.y * 64;
  const int wm = (wave >> 1) * 32, wn = (wave & 1) * 64;   // wave sub-tile: 32(b) x 64(d)
  const int srow = tid >> 2, skp = tid & 3;  // staging: row=tid>>2, 16B kpart=tid&3
  f32x4 acc[2][4] = {};

  for (int kt = 0; kt < D_MODEL / 32; ++kt) {
    const int k0 = kt * 32;
    gld_lds16(xb + (size_t)(b0 + srow) * D_MODEL + k0 + skp * 8, As + wave * 512);
    gld_lds16(wdb + (size_t)(d0 + srow) * D_MODEL + k0 + skp * 8, Bs + wave * 512);
    gld_lds16(wdb + (size_t)(d0 + 64 + srow) * D_MODEL + k0 + skp * 8, Bs + 2048 + wave * 512);
    __syncthreads();
    bf16x8 af[2], bf[4];
#pragma unroll
    for (int i = 0; i < 2; ++i)
      af[i] = __builtin_bit_cast(bf16x8, *(const short8*)(As + (wm + i * 16 + r16) * 32 + q * 8));
#pragma unroll
    for (int j = 0; j < 4; ++j)
      bf[j] = __builtin_bit_cast(bf16x8, *(const short8*)(Bs + (wn + j * 16 + r16) * 32 + q * 8));
#pragma unroll
    for (int i = 0; i < 2; ++i)
#pragma unroll
      for (int j = 0; j < 4; ++j)
        acc[i][j] = __builtin_amdgcn_mfma_f32_16x16x32_bf16(af[i], bf[j], acc[i][j], 0, 0, 0);
    __syncthreads();
  }
  {  // augmented K-step (K=32): acc += ev @ We.T
    gld_lds16(evb + (size_t)(b0 + srow) * D_EVENT + skp * 8, As + wave * 512);
    gld_lds16(web + (size_t)(d0 + srow) * D_EVENT + skp * 8, Bs + wave * 512);
    gld_lds16(web + (size_t)(d0 + 64 + srow) * D_EVENT + skp * 8, Bs + 2048 + wave * 512);
    __syncthreads();
    bf16x8 af[2], bf[4];
#pragma unroll
    for (int i = 0; i < 2; ++i)
      af[i] = __builtin_bit_cast(bf16x8, *(const short8*)(As + (wm + i * 16 + r16) * 32 + q * 8));
#pragma unroll
    for (int j = 0; j < 4; ++j)
      bf[j] = __builtin_bit_cast(bf16x8, *(const short8*)(Bs + (wn + j * 16 + r16) * 32 + q * 8));
#pragma unroll
    for (int i = 0; i < 2; ++i)
#pragma unroll
      for (int j = 0; j < 4; ++j)
        acc[i][j] = __builtin_amdgcn_mfma_f32_16x16x32_bf16(af[i], bf[j], acc[i][j], 0, 0, 0);
  }
  // epilogue: + bd, softplus, clamp 2.0. C/D layout: col=lane&15 -> d, row=(lane>>4)*4+reg -> b
#pragma unroll
  for (int j = 0; j < 4; ++j) {
    const int d = d0 + wn + j * 16 + r16;
    const float bdv = bd[d];
#pragma unroll
    for (int i = 0; i < 2; ++i) {
      const int brow = b0 + wm + i * 16 + q * 4;
#pragma unroll
      for (int r = 0; r < 4; ++r) {
        float pre = acc[i][j][r] + bdv;
        float sp = fmaxf(pre, 0.f) + log1pf(__expf(-fabsf(pre)));
        delta[(size_t)(brow + r) * D_MODEL + d] = fminf(sp, 2.0f);
      }
    }
  }
}

// ---------------------------------------------------------------------------
// Kernel 4 (v2): state update + y. 1 lane per (b,d): 16 states (4 f32x4) per
// lane, 64 B/lane loads+stores, delta/x read once, pole dot fully in-lane
// (32 MACs, no shuffles). Massively parallel (16384 blocks) -> HBM-bound.
// ---------------------------------------------------------------------------
__global__ __launch_bounds__(256) void update_kernel(
    const float* __restrict__ hprev, const float* __restrict__ x,
    const float* __restrict__ ev, const float* __restrict__ AWe,
    const float* __restrict__ Dv,
    const float* __restrict__ delta, const float* __restrict__ abase,
    const float* __restrict__ Bt, const float* __restrict__ Ct,
    float* __restrict__ y, float* __restrict__ h)
{
  const int pid = blockIdx.x * 256 + threadIdx.x;
  const int b = pid >> 11, d = pid & (D_MODEL - 1);
  const float dlt = delta[pid];
  const float xv = x[pid];

  // pole = dot(ev[b,:32], AWe[d,:32])
  const f32x4* evp = (const f32x4*)(ev + (size_t)b * D_EVENT);
  const f32x4* awp = (const f32x4*)(AWe + (size_t)d * D_EVENT);
  float p = 0.f;
#pragma unroll
  for (int m = 0; m < 8; ++m) {
    f32x4 e = evp[m], a = awp[m];
    p += e[0]*a[0] + e[1]*a[1] + e[2]*a[2] + e[3]*a[3];
  }

  const float dl2 = dlt * 1.4426950408889634f;  // delta * log2(e)
  const float bx = dlt * xv;
  const f32x4* hp4 = (const f32x4*)(hprev + (size_t)pid * D_STATE);
  const f32x4* ab4 = (const f32x4*)(abase + (size_t)d * D_STATE);
  const f32x4* bt4 = (const f32x4*)(Bt + (size_t)b * D_STATE);
  const f32x4* ct4 = (const f32x4*)(Ct + (size_t)b * D_STATE);
  f32x4* hn4 = (f32x4*)(h + (size_t)pid * D_STATE);
  float yp = 0.f;
#pragma unroll
  for (int s = 0; s < 4; ++s) {
    f32x4 hp = hp4[s], ab = ab4[s], bt = bt4[s], ct = ct4[s], hn;
#pragma unroll
    for (int u = 0; u < 4; ++u) {
      float abar = exp2f(dl2 * (ab[u] + p));
      float hv = abar * hp[u] + bx * bt[u];
      hn[u] = hv;
      yp += hv * ct[u];
    }
    hn4[s] = hn;
  }
  y[pid] = yp + Dv[d] * xv;
}

// ---------------------------------------------------------------------------
extern "C" void kernel_launch(void* const* d_in, const int* in_sizes, int n_in,
                              void* d_out, int out_size, void* d_ws, size_t ws_size,
                              hipStream_t stream) {
  const float* x     = (const float*)d_in[0];
  const float* hprev = (const float*)d_in[1];
  const float* ev    = (const float*)d_in[2];
  const float* alog  = (const float*)d_in[3];
  const float* Dv    = (const float*)d_in[4];
  const float* Wd    = (const float*)d_in[5];
  const float* bd    = (const float*)d_in[6];
  const float* We    = (const float*)d_in[7];
  const float* BW1   = (const float*)d_in[8];
  const float* Bb1   = (const float*)d_in[9];
  const float* BW2   = (const float*)d_in[10];
  const float* Bb2   = (const float*)d_in[11];
  const float* BWe   = (const float*)d_in[12];
  const float* AWe   = (const float*)d_in[13];
  const float* CW    = (const float*)d_in[14];

  float* y = (float*)d_out;                           // (B, D_MODEL)
  float* h = (float*)d_out + (size_t)BATCH * D_MODEL; // (B, D_MODEL, D_STATE)

  // workspace layout (bytes): ~33 MiB total
  char* ws = (char*)d_ws;
  unsigned short* xb  = (unsigned short*)(ws);                      // 8 MiB
  unsigned short* wdb = (unsigned short*)(ws + (8u << 20));         // 8 MiB
  float* delta        = (float*)(ws + (16u << 20));                 // 16 MiB
  float* Bt           = (float*)(ws + (32u << 20));                 // 128 KiB
  float* Ct           = (float*)(ws + (32u << 20) + (128u << 10));  // 128 KiB
  float* abase        = (float*)(ws + (32u << 20) + (256u << 10));  // 128 KiB
  unsigned short* evb = (unsigned short*)(ws + (32u << 20) + (384u << 10)); // 128 KiB
  unsigned short* web = (unsigned short*)(ws + (32u << 20) + (512u << 10)); // 128 KiB

  hipLaunchKernelGGL(prep_kernel, dim3((BATCH * D_MODEL) / 4 / 256), dim3(256), 0, stream,
                     x, Wd, ev, We, alog, xb, wdb, evb, web, abase);
  hipLaunchKernelGGL(bc_kernel, dim3(BATCH / 4), dim3(256), 0, stream,
                     x, ev, BW1, Bb1, BW2, Bb2, BWe, CW, Bt, Ct);
  hipLaunchKernelGGL(gemm_delta, dim3(D_MODEL / 128, BATCH / 64), dim3(256), 0, stream,
                     xb, wdb, evb, web, bd, delta);
  hipLaunchKernelGGL(update_kernel, dim3((BATCH * D_MODEL) / 256), dim3(256), 0, stream,
                     hprev, x, ev, AWe, Dv, delta, abase, Bt, Ct, y, h);
}